// Round 1
// baseline (1002.384 us; speedup 1.0000x reference)
//
#include <hip/hip_runtime.h>
#include <hip/hip_bf16.h>

// Problem constants (match reference)
#define NN 8192
#define KK 64
#define CARD 64
// ws layout (float offsets)
#define AST_OFF   0          // [64][8192] AS^T, 524288 floats
#define CRAW_OFF  524288     // [64][64]  CRAW[j*64+l] = C_ref[l][j]
#define DGM0_OFF  528384     // [64][2]
#define DGM1_OFF  528512     // [64][2]

__device__ __forceinline__ float rlane(float v, int l) {
  return __int_as_float(__builtin_amdgcn_readlane(__float_as_int(v), l));
}
__device__ __forceinline__ double rdlane(double x, int l) {
  int lo = __builtin_amdgcn_readlane(__double2loint(x), l);
  int hi = __builtin_amdgcn_readlane(__double2hiint(x), l);
  return __hiloint2double(hi, lo);
}

// ---------------------------------------------------------------------------
// K1: AS^T[j][row] += A @ S over a k-split chunk.
// 256 thr = 4 waves; wave = 16-col group (cg); lane = base row; 4 rows/lane
// (rows lane, lane+64, lane+128, lane+192) -> 64 fma per 8 LDS reads.
// A tile k-major in LDS (conflict-free b32); S tile in LDS, wave-uniform
// b128 broadcast reads. grid = 32 rowblocks * 16 ksplit = 512 (2 blocks/CU).
// ---------------------------------------------------------------------------
#define KSPLIT 16
#define KT 32
#define RB 256
__global__ __launch_bounds__(256, 2) void k_gemm_as(
    const float* __restrict__ A, const float* __restrict__ S,
    float* __restrict__ AST) {
  __shared__ float At[KT][RB + 1];   // k-major: At[k][row], 32.9 KB
  __shared__ float Sl[KT][64];       // 8 KB
  const int tid = threadIdx.x;
  const int rb = blockIdx.x >> 4;
  const int ks = blockIdx.x & 15;
  const int r0 = rb * RB;
  const int lane = tid & 63;
  const int cg = __builtin_amdgcn_readfirstlane(tid >> 6);
  const int c0 = cg * 16;

  float acc[4][16];
#pragma unroll
  for (int r = 0; r < 4; ++r)
#pragma unroll
    for (int q = 0; q < 16; ++q) acc[r][q] = 0.0f;

  const int kbeg = ks * (NN / KSPLIT);  // 512 k per block
  for (int kt = kbeg; kt < kbeg + NN / KSPLIT; kt += KT) {
    // stage A: 256 rows x 32 k = 2048 float4, 8 per thread
#pragma unroll
    for (int p = 0; p < 8; ++p) {
      int fi = p * 256 + tid;
      int rr = fi >> 3, cc = (fi & 7) * 4;
      float4 v = *reinterpret_cast<const float4*>(
          A + (size_t)(r0 + rr) * NN + kt + cc);
      At[cc + 0][rr] = v.x; At[cc + 1][rr] = v.y;
      At[cc + 2][rr] = v.z; At[cc + 3][rr] = v.w;
    }
    // stage S: 32 k x 64 cols = 512 float4, 2 per thread
#pragma unroll
    for (int p = 0; p < 2; ++p) {
      int fi = p * 256 + tid;
      int rr = fi >> 4, cc = (fi & 15) * 4;
      float4 v = *reinterpret_cast<const float4*>(
          S + (size_t)(kt + rr) * KK + cc);
      *reinterpret_cast<float4*>(&Sl[rr][cc]) = v;
    }
    __syncthreads();
#pragma unroll 2
    for (int k = 0; k < KT; ++k) {
      float a0 = At[k][lane];
      float a1 = At[k][lane + 64];
      float a2 = At[k][lane + 128];
      float a3 = At[k][lane + 192];
      const float4* Sv = reinterpret_cast<const float4*>(&Sl[k][c0]);
      float4 s0 = Sv[0], s1 = Sv[1], s2 = Sv[2], s3 = Sv[3];
      float sc[16] = {s0.x, s0.y, s0.z, s0.w, s1.x, s1.y, s1.z, s1.w,
                      s2.x, s2.y, s2.z, s2.w, s3.x, s3.y, s3.z, s3.w};
#pragma unroll
      for (int q = 0; q < 16; ++q) {
        acc[0][q] = fmaf(a0, sc[q], acc[0][q]);
        acc[1][q] = fmaf(a1, sc[q], acc[1][q]);
        acc[2][q] = fmaf(a2, sc[q], acc[2][q]);
        acc[3][q] = fmaf(a3, sc[q], acc[3][q]);
      }
    }
    __syncthreads();
  }
#pragma unroll
  for (int r = 0; r < 4; ++r)
#pragma unroll
    for (int q = 0; q < 16; ++q)
      unsafeAtomicAdd(&AST[(size_t)(c0 + q) * NN + r0 + r * 64 + lane],
                      acc[r][q]);
}

// ---------------------------------------------------------------------------
// K2: CRAW[j*64+l] += sum_i S[i][l] * AST[j][i]  over an i-segment.
// ---------------------------------------------------------------------------
__global__ __launch_bounds__(256) void k_gemm_c(
    const float* __restrict__ S, const float* __restrict__ AST,
    float* __restrict__ CRAW) {
  const int j = blockIdx.x & 63;
  const int iseg = blockIdx.x >> 6;
  const int lane = threadIdx.x & 63;
  const int s4 = __builtin_amdgcn_readfirstlane(threadIdx.x >> 6);
  const int i0 = iseg * 1024 + s4 * 256;
  const float* astj = AST + (size_t)j * NN + i0;
  float acc = 0.0f;
  for (int i = 0; i < 256; i += 4) {
    float4 a4 = *reinterpret_cast<const float4*>(astj + i);
    const float* Srow = S + (size_t)(i0 + i) * KK + lane;
    acc = fmaf(a4.x, Srow[0 * KK], acc);
    acc = fmaf(a4.y, Srow[1 * KK], acc);
    acc = fmaf(a4.z, Srow[2 * KK], acc);
    acc = fmaf(a4.w, Srow[3 * KK], acc);
  }
  __shared__ float red[4][64];
  red[s4][lane] = acc;
  __syncthreads();
  if (threadIdx.x < 64) {
    unsafeAtomicAdd(&CRAW[j * 64 + lane],
                    red[0][lane] + red[1][lane] + red[2][lane] + red[3][lane]);
  }
}

// ---------------------------------------------------------------------------
// K3: D build + Prim MST + dgm0 + dgm1 (one block, LDS-resident).
// Also zeroes d_out for K4's atomic adds.
// ---------------------------------------------------------------------------
__global__ __launch_bounds__(256) void k_topo(
    const float* __restrict__ CRAW, float* __restrict__ DGM0,
    float* __restrict__ DGM1, float* __restrict__ out) {
  __shared__ float Dl[64 * 66];
  __shared__ float red[4];
  __shared__ float wsE[64];
  __shared__ int usE[64], vsE[64];
  __shared__ unsigned char msk[4096];
  __shared__ float death[4096];
  __shared__ float pers[4096];
  __shared__ float rv[4];
  __shared__ int ri[4];
  const int t = threadIdx.x;

  if (t == 0) out[0] = 0.0f;

  // 1) symmetrize + global max
  float lmax = -1e30f;
#pragma unroll
  for (int m = 0; m < 16; ++m) {
    int idx = t + 256 * m;
    int a = idx >> 6, b = idx & 63;
    float v = 0.5f * (CRAW[idx] + CRAW[b * 64 + a]);
    Dl[a * 66 + b] = v;
    lmax = fmaxf(lmax, v);
  }
  for (int o = 32; o > 0; o >>= 1) lmax = fmaxf(lmax, __shfl_xor(lmax, o));
  if ((t & 63) == 0) red[t >> 6] = lmax;
  __syncthreads();
  const float mx = fmaxf(fmaxf(red[0], red[1]), fmaxf(red[2], red[3]));
  const float inv = 1.0f / (mx + 1e-12f);
  __syncthreads();
#pragma unroll
  for (int m = 0; m < 16; ++m) {
    int idx = t + 256 * m;
    int a = idx >> 6, b = idx & 63;
    float v = 1.0f - Dl[a * 66 + b] * inv;
    Dl[a * 66 + b] = (a == b) ? 0.0f : v;
  }
  __syncthreads();

  // 2) Prim MST in wave 0 (lane = vertex v)
  if (t < 64) {
    const int lane = t;
    bool intree = (lane == 0);
    float key = Dl[0 * 66 + lane];
    int par = 0;
    for (int step = 0; step < 63; ++step) {
      float kv = intree ? 1e9f : key;
      int ki = lane;
      for (int o = 32; o > 0; o >>= 1) {
        float ov = __shfl_xor(kv, o);
        int oi = __shfl_xor(ki, o);
        if (ov < kv || (ov == kv && oi < ki)) { kv = ov; ki = oi; }
      }
      int pu = __shfl(par, ki);
      if (lane == 0) { wsE[step] = kv; usE[step] = pu; vsE[step] = ki; }
      if (lane == ki) intree = true;
      float dn = Dl[ki * 66 + lane];
      if (!intree && dn < key) { key = dn; par = ki; }
    }
  }
  __syncthreads();

  // 3) MST adjacency mask
  for (int idx = t; idx < 4096; idx += 256) msk[idx] = 0;
  __syncthreads();
  if (t < 63) {
    int u = usE[t], v = vsE[t];
    msk[u * 64 + v] = 1;
    msk[v * 64 + u] = 1;
  }
  __syncthreads();

  // 4) dgm0: rank-sort descending of [ws(63), 0]
  if (t < 64) {
    float wv = (t < 63) ? wsE[t] : 0.0f;
    int rank = 0;
    for (int o = 0; o < 64; ++o) {
      float wo = (o < 63) ? wsE[o] : 0.0f;
      rank += (wo > wv) || (wo == wv && o < t);
    }
    DGM0[rank * 2 + 0] = 0.0f;
    DGM0[rank * 2 + 1] = wv;
  }

  // 5) death & persistence for all pairs
  for (int p = t; p < 4096; p += 256) {
    int i = p >> 6, j = p & 63;
    float dij = Dl[i * 66 + j];
    float tmin = 1e9f;
#pragma unroll 8
    for (int k2 = 0; k2 < 64; ++k2) {
      float m2 = fmaxf(Dl[i * 66 + k2], Dl[j * 66 + k2]);
      tmin = fminf(tmin, (k2 == i || k2 == j) ? 1e9f : m2);
    }
    float de = fmaxf(dij, tmin);
    death[p] = de;
    bool valid = (j > i) && (!msk[p]);
    pers[p] = valid ? (de - dij) : -1.0f;
  }
  __syncthreads();

  // 6) top-64 of pers (lowest-index ties), write dgm1
  for (int r = 0; r < 64; ++r) {
    float bv = -1e30f;
    int bi = 0;
    for (int p = t; p < 4096; p += 256) {
      float v = pers[p];
      if (v > bv) { bv = v; bi = p; }
    }
    for (int o = 32; o > 0; o >>= 1) {
      float ov = __shfl_xor(bv, o);
      int oi = __shfl_xor(bi, o);
      if (ov > bv || (ov == bv && oi < bi)) { bv = ov; bi = oi; }
    }
    if ((t & 63) == 0) { rv[t >> 6] = bv; ri[t >> 6] = bi; }
    __syncthreads();
    if (t == 0) {
      for (int q = 1; q < 4; ++q)
        if (rv[q] > bv || (rv[q] == bv && ri[q] < bi)) { bv = rv[q]; bi = ri[q]; }
      bool keep = bv > 0.0f;
      int i = bi >> 6, j = bi & 63;
      DGM1[r * 2 + 0] = keep ? Dl[i * 66 + j] : 0.0f;
      DGM1[r * 2 + 1] = keep ? death[bi] : 0.0f;
      pers[bi] = -3.0f;
    }
    __syncthreads();
  }
}

// ---------------------------------------------------------------------------
// K4: Sinkhorn W1 (65x65, 300 iters), multiplicative domain, fp64.
// SINGLE WAVE per problem, zero barriers in the 300-iter loop.
// Lane i carries row i of W (phase u) and column i of W (phase v) in
// registers (2x65 fp64 = 260 VGPR; launch_bounds(64,1) -> 512-VGPR budget).
// Per j: v_j broadcast via 2x v_readlane + 1x v_fma_f64 (SGPR-pair operand).
// Row/col-64 mass terms: one lane-product + 6-step shfl_xor f64 butterfly;
// their ~200-cyc latency is consumed a full phase later (u64 only needed at
// the END of phase v; v64 at the END of next phase u) so it hides under the
// FMA stream. fp64 because |log| <= C_max/eps + log64 ~ 105 (overflows fp32).
// ---------------------------------------------------------------------------
__global__ __launch_bounds__(64, 1) void k_sinkhorn(
    const float* __restrict__ DGM0, const float* __restrict__ DGM1,
    const float* __restrict__ G0, const float* __restrict__ G1,
    const float* __restrict__ G2, const float* __restrict__ G3,
    float* __restrict__ out) {
  const int b = blockIdx.x;
  const float* X = (b & 1) ? DGM1 : DGM0;
  const float* Y = (b == 0) ? G0 : (b == 1) ? G1 : (b == 2) ? G2 : G3;

  __shared__ float Cf[65][66];    // C/eps (setup + final loss), 17.2 KB
  __shared__ double Wd[65][66];   // exp(-C/eps), 34.3 KB (setup only)

  const int lane = threadIdx.x;   // 0..63, one wave
  const float INVE = 100.0f;      // 1/eps

  // ---- setup: C/eps into LDS ----
  for (int idx = lane; idx < 65 * 65; idx += 64) {
    int i = idx / 65, j = idx - i * 65;
    float v;
    if (i < 64) {
      float xb = X[i * 2], xd = X[i * 2 + 1];
      if (j < 64)
        v = fmaxf(fabsf(xb - Y[j * 2]), fabsf(xd - Y[j * 2 + 1]));
      else
        v = 0.5f * (xd - xb);
    } else {
      v = (j < 64) ? 0.5f * (Y[j * 2 + 1] - Y[j * 2]) : 0.0f;
    }
    Cf[i][j] = v * INVE;
  }
  __syncthreads();
  // ---- W = exp(-C/eps), computed once cooperatively (4225 exps / wave) ----
  for (int idx = lane; idx < 65 * 65; idx += 64) {
    int i = idx / 65, j = idx - i * 65;
    Wd[i][j] = exp(-(double)Cf[i][j]);
  }
  __syncthreads();

  // ---- register-resident W: row lane (phase u) + column lane (phase v) ----
  double WF[64], WG[64];
#pragma unroll
  for (int j = 0; j < 64; ++j) WF[j] = Wd[lane][j];   // W[lane][j]
#pragma unroll
  for (int i = 0; i < 64; ++i) WG[i] = Wd[i][lane];   // W[i][lane]
  const double WF8  = Wd[lane][64];   // W[lane][64]
  const double W64r = Wd[64][lane];   // W[64][lane]

  double u = 1.0, v = 1.0, u64 = 1.0, v64 = 1.0;

  for (int it = 0; it < 300; ++it) {
    // ---- cross-lane mass-row sum: t64 = sum_j W[64][j] v_j (latency-hidden)
    double t64 = W64r * v;
#pragma unroll
    for (int o = 32; o > 0; o >>= 1) t64 += __shfl_xor(t64, o);

    // ---- phase u main: s_i = sum_{j<64} W[i][j] v_j  (i = lane) ----
    double a0 = 0.0, a1 = 0.0, a2 = 0.0, a3 = 0.0;
#pragma unroll
    for (int j = 0; j < 64; j += 4) {
      a0 = fma(WF[j + 0], rdlane(v, j + 0), a0);
      a1 = fma(WF[j + 1], rdlane(v, j + 1), a1);
      a2 = fma(WF[j + 2], rdlane(v, j + 2), a2);
      a3 = fma(WF[j + 3], rdlane(v, j + 3), a3);
    }
    double s = ((a0 + a1) + (a2 + a3)) + WF8 * v64;
    u = 1.0 / s;                       // a_i = 1 for i < 64
    u64 = 64.0 / (t64 + v64);          // W[64][64] = 1

    // ---- cross-lane mass-col sum: t8 = sum_i W[i][64] u_i (latency-hidden)
    double t8 = WF8 * u;
#pragma unroll
    for (int o = 32; o > 0; o >>= 1) t8 += __shfl_xor(t8, o);

    // ---- phase v main: s_j = sum_{i<64} W[i][j] u_i  (j = lane) ----
    double b0 = 0.0, b1 = 0.0, b2 = 0.0, b3 = 0.0;
#pragma unroll
    for (int i = 0; i < 64; i += 4) {
      b0 = fma(WG[i + 0], rdlane(u, i + 0), b0);
      b1 = fma(WG[i + 1], rdlane(u, i + 1), b1);
      b2 = fma(WG[i + 2], rdlane(u, i + 2), b2);
      b3 = fma(WG[i + 3], rdlane(u, i + 3), b3);
    }
    double sv = ((b0 + b1) + (b2 + b3)) + W64r * u64;
    v = 1.0 / sv;                      // b_j = 1 for j < 64
    v64 = 64.0 / (t8 + u64);
  }

  // ---- final: loss = eps * sum_ij u_i W_ij v_j * (C_ij/eps) ----
  double acc = 0.0;
#pragma unroll
  for (int j = 0; j < 64; ++j)
    acc += u * WF[j] * rdlane(v, j) * (double)Cf[lane][j];   // rows = lane
  acc += u * WF8 * v64 * (double)Cf[lane][64];               // col 64
  acc += u64 * W64r * v * (double)Cf[64][lane];              // row 64
  // (64,64): C = 0 contributes nothing
  float af = (float)acc;
#pragma unroll
  for (int o = 32; o > 0; o >>= 1) af += __shfl_xor(af, o);
  if (lane == 0)
    atomicAdd(out, 0.1f * 0.01f * af);  // LAMBDA * eps * sum(P * C/eps)
}

// ---------------------------------------------------------------------------
extern "C" void kernel_launch(void* const* d_in, const int* in_sizes, int n_in,
                              void* d_out, int out_size, void* d_ws,
                              size_t ws_size, hipStream_t stream) {
  const float* A = (const float*)d_in[0];
  const float* S = (const float*)d_in[1];
  const float* G0 = (const float*)d_in[2];
  const float* G1 = (const float*)d_in[3];
  const float* G2 = (const float*)d_in[4];
  const float* G3 = (const float*)d_in[5];
  float* out = (float*)d_out;
  float* ws = (float*)d_ws;

  float* AST = ws + AST_OFF;
  float* CRAW = ws + CRAW_OFF;
  float* DGM0 = ws + DGM0_OFF;
  float* DGM1 = ws + DGM1_OFF;

  // zero AST (2 MB) + CRAW (16 KB) for atomic accumulation
  (void)hipMemsetAsync(AST, 0, (size_t)(64 * NN + 64 * 64) * sizeof(float),
                       stream);

  k_gemm_as<<<dim3(32 * KSPLIT), dim3(256), 0, stream>>>(A, S, AST);
  k_gemm_c<<<dim3(64 * 8), dim3(256), 0, stream>>>(S, AST, CRAW);
  k_topo<<<dim3(1), dim3(256), 0, stream>>>(CRAW, DGM0, DGM1, out);
  k_sinkhorn<<<dim3(4), dim3(64), 0, stream>>>(DGM0, DGM1, G0, G1, G2, G3,
                                               out);
}